// Round 1
// baseline (970.464 us; speedup 1.0000x reference)
//
#include <hip/hip_runtime.h>
#include <math.h>

#define NN 100000
#define NE 1600000

__device__ __forceinline__ float sigm(float z) { return 1.0f / (1.0f + expf(-z)); }

__global__ __launch_bounds__(256) void k_deg(const int* __restrict__ row,
                                             const float* __restrict__ ew,
                                             float* __restrict__ deg) {
  int e = blockIdx.x * 256 + threadIdx.x;
  if (e < NE) unsafeAtomicAdd(&deg[row[e]], ew[e]);
}

__global__ __launch_bounds__(256) void k_dis(const float* __restrict__ deg,
                                             float* __restrict__ dis) {
  int n = blockIdx.x * 256 + threadIdx.x;
  if (n < NN) {
    float d = deg[n];
    dis[n] = d > 0.0f ? rsqrtf(d) : 0.0f;
  }
}

__global__ __launch_bounds__(256) void k_wnorm(const int* __restrict__ row,
                                               const int* __restrict__ col,
                                               const float* __restrict__ ew,
                                               const float* __restrict__ dis,
                                               float* __restrict__ wn) {
  int e = blockIdx.x * 256 + threadIdx.x;
  if (e < NE) wn[e] = dis[row[e]] * ew[e] * dis[col[e]];
}

// 8 threads per edge; each handles 4 contiguous features (float4 gather of h).
__global__ __launch_bounds__(256) void k_scatter(const int* __restrict__ row,
                                                 const int* __restrict__ col,
                                                 const float* __restrict__ wn,
                                                 const float4* __restrict__ h4,
                                                 float* __restrict__ agg) {
  int tid = blockIdx.x * 256 + threadIdx.x;
  int e = tid >> 3;
  if (e >= NE) return;
  int s = tid & 7;
  float w = wn[e];
  int cc = col[e];
  int rr = row[e];
  float4 hv = h4[cc * 8 + s];
  float* dst = agg + rr * 32 + s * 4;
  unsafeAtomicAdd(dst + 0, w * hv.x);
  unsafeAtomicAdd(dst + 1, w * hv.y);
  unsafeAtomicAdd(dst + 2, w * hv.z);
  unsafeAtomicAdd(dst + 3, w * hv.w);
}

struct GateParams {
  const float4* x4;    // [N][16]
  const float4* h4;    // [N][8]
  const float4* c4;    // [N][8]
  const float4* agg4;  // [N][8]
  const float4* W[4];  // [64][8] each
  const float* b[4];   // [32]
  const float4* T0[4]; // [32][8]
  const float4* T1[4]; // [32][8]
  const float* cb[4];  // [32]
  const float* Wlin;   // [32]
  const float* blin;   // [1]
  float* out;          // [N]
};

// Block = 256 threads. Thread layout: fg = tid&7 (feature quad), ng = tid>>3
// (node-group). Each thread: 4 nodes x 4 features x 4 gates. One ds_read_b128
// weight fetch feeds 16 FMAs (4 nodes x 4 components).
__global__ __launch_bounds__(256) void k_gates(GateParams p) {
  __shared__ float4 sW[4][64][8];   // 32 KB
  __shared__ float4 sT0[4][32][8];  // 16 KB
  __shared__ float4 sT1[4][32][8];  // 16 KB
  __shared__ float sBias[4][32];
  __shared__ float sWlin[32];
  __shared__ float sBlin;

  const int t = threadIdx.x;
#pragma unroll
  for (int g = 0; g < 4; ++g) {
    float4* dW = &sW[g][0][0];
    for (int i = t; i < 512; i += 256) dW[i] = p.W[g][i];
    (&sT0[g][0][0])[t] = p.T0[g][t];
    (&sT1[g][0][0])[t] = p.T1[g][t];
  }
  if (t < 32) {
#pragma unroll
    for (int g = 0; g < 4; ++g) sBias[g][t] = p.b[g][t] + p.cb[g][t];
    sWlin[t] = p.Wlin[t];
  }
  if (t == 0) sBlin = p.blin[0];
  __syncthreads();

  const int fg = t & 7;
  const int ng = t >> 3;
  const int nb = (blockIdx.x * 32 + ng) * 4;

  int nidx[4];
#pragma unroll
  for (int j = 0; j < 4; ++j) {
    int n = nb + j;
    nidx[j] = n < NN ? n : 0;
  }

  float4 acc[4][4];  // [node][gate]
#pragma unroll
  for (int j = 0; j < 4; ++j) {
#pragma unroll
    for (int g = 0; g < 4; ++g) {
      acc[j][g].x = sBias[g][fg * 4 + 0];
      acc[j][g].y = sBias[g][fg * 4 + 1];
      acc[j][g].z = sBias[g][fg * 4 + 2];
      acc[j][g].w = sBias[g][fg * 4 + 3];
    }
  }

  // x @ W part (K = 64)
  for (int k4 = 0; k4 < 16; ++k4) {
    float4 xv[4];
#pragma unroll
    for (int j = 0; j < 4; ++j) xv[j] = p.x4[nidx[j] * 16 + k4];
#pragma unroll
    for (int kk = 0; kk < 4; ++kk) {
#pragma unroll
      for (int g = 0; g < 4; ++g) {
        float4 w = sW[g][k4 * 4 + kk][fg];
#pragma unroll
        for (int j = 0; j < 4; ++j) {
          float xs = (&xv[j].x)[kk];
          acc[j][g].x = fmaf(xs, w.x, acc[j][g].x);
          acc[j][g].y = fmaf(xs, w.y, acc[j][g].y);
          acc[j][g].z = fmaf(xs, w.z, acc[j][g].z);
          acc[j][g].w = fmaf(xs, w.w, acc[j][g].w);
        }
      }
    }
  }

  // h @ theta0 - agg @ theta1 part (K = 32)
  for (int k4 = 0; k4 < 8; ++k4) {
    float4 hv[4], av[4];
#pragma unroll
    for (int j = 0; j < 4; ++j) {
      hv[j] = p.h4[nidx[j] * 8 + k4];
      av[j] = p.agg4[nidx[j] * 8 + k4];
    }
#pragma unroll
    for (int kk = 0; kk < 4; ++kk) {
#pragma unroll
      for (int g = 0; g < 4; ++g) {
        float4 t0 = sT0[g][k4 * 4 + kk][fg];
        float4 t1 = sT1[g][k4 * 4 + kk][fg];
#pragma unroll
        for (int j = 0; j < 4; ++j) {
          float hs = (&hv[j].x)[kk];
          float as = (&av[j].x)[kk];
          acc[j][g].x = fmaf(hs, t0.x, acc[j][g].x);
          acc[j][g].y = fmaf(hs, t0.y, acc[j][g].y);
          acc[j][g].z = fmaf(hs, t0.z, acc[j][g].z);
          acc[j][g].w = fmaf(hs, t0.w, acc[j][g].w);
          acc[j][g].x = fmaf(-as, t1.x, acc[j][g].x);
          acc[j][g].y = fmaf(-as, t1.y, acc[j][g].y);
          acc[j][g].z = fmaf(-as, t1.z, acc[j][g].z);
          acc[j][g].w = fmaf(-as, t1.w, acc[j][g].w);
        }
      }
    }
  }

  // Epilogue: gates, cell update, ReLU, dot with W_lin, 8-lane reduce.
#pragma unroll
  for (int j = 0; j < 4; ++j) {
    float4 cv = p.c4[nidx[j] * 8 + fg];
    float partial = 0.0f;
#pragma unroll
    for (int kk = 0; kk < 4; ++kk) {
      float zi = (&acc[j][0].x)[kk];
      float zf = (&acc[j][1].x)[kk];
      float zc = (&acc[j][2].x)[kk];
      float zo = (&acc[j][3].x)[kk];
      float ccv = (&cv.x)[kk];
      float I = sigm(zi);
      float F = sigm(zf);
      float T = tanhf(zc);
      float O = sigm(zo);
      float C = fmaf(F, ccv, I * T);
      float H = O * tanhf(C);
      float r = fmaxf(H, 0.0f);
      partial = fmaf(r, sWlin[fg * 4 + kk], partial);
    }
    partial += __shfl_down(partial, 4, 8);
    partial += __shfl_down(partial, 2, 8);
    partial += __shfl_down(partial, 1, 8);
    if (fg == 0 && nb + j < NN) p.out[nb + j] = partial + sBlin;
  }
}

extern "C" void kernel_launch(void* const* d_in, const int* in_sizes, int n_in,
                              void* d_out, int out_size, void* d_ws, size_t ws_size,
                              hipStream_t stream) {
  const float* x = (const float*)d_in[0];
  const int* row = (const int*)d_in[1];
  const int* col = row + NE;
  const float* ew = (const float*)d_in[2];
  const float* h = (const float*)d_in[3];
  const float* c = (const float*)d_in[4];

  float* ws = (float*)d_ws;
  float* deg = ws;                 // N
  float* dis = ws + NN;            // N
  float* wn = ws + 2 * NN;         // E
  float* agg = ws + 2 * NN + NE;   // N*32  (offset is 16B-aligned)

  hipMemsetAsync(deg, 0, NN * sizeof(float), stream);
  hipMemsetAsync(agg, 0, (size_t)NN * 32 * sizeof(float), stream);

  k_deg<<<(NE + 255) / 256, 256, 0, stream>>>(row, ew, deg);
  k_dis<<<(NN + 255) / 256, 256, 0, stream>>>(deg, dis);
  k_wnorm<<<(NE + 255) / 256, 256, 0, stream>>>(row, col, ew, dis, wn);
  k_scatter<<<(NE * 8) / 256, 256, 0, stream>>>(row, col, wn, (const float4*)h, agg);

  GateParams p;
  p.x4 = (const float4*)x;
  p.h4 = (const float4*)h;
  p.c4 = (const float4*)c;
  p.agg4 = (const float4*)agg;
  for (int g = 0; g < 4; ++g) {
    p.W[g] = (const float4*)d_in[5 + 4 * g];
    p.b[g] = (const float*)d_in[6 + 4 * g];
    p.T0[g] = (const float4*)d_in[7 + 4 * g];
    p.T1[g] = p.T0[g] + 256;
    p.cb[g] = (const float*)d_in[8 + 4 * g];
  }
  p.Wlin = (const float*)d_in[21];
  p.blin = (const float*)d_in[22];
  p.out = (float*)d_out;

  k_gates<<<(NN + 127) / 128, 256, 0, stream>>>(p);
}

// Round 2
// 525.985 us; speedup vs baseline: 1.8450x; 1.8450x over previous
//
#include <hip/hip_runtime.h>
#include <math.h>

#define NN 100000
#define NE 1600000
#define NBLK 391  // ceil(NN/256)

__device__ __forceinline__ float sigm(float z) { return 1.0f / (1.0f + expf(-z)); }

// Phase 1: edge histogram (int count) + weighted degree, both atomically.
__global__ __launch_bounds__(256) void k_hist(const int* __restrict__ row,
                                              const float* __restrict__ ew,
                                              int* __restrict__ cnt,
                                              float* __restrict__ deg) {
  int e = blockIdx.x * 256 + threadIdx.x;
  if (e < NE) {
    int r = row[e];
    atomicAdd(&cnt[r], 1);
    unsafeAtomicAdd(&deg[r], ew[e]);
  }
}

__global__ __launch_bounds__(256) void k_dis(const float* __restrict__ deg,
                                             float* __restrict__ dis) {
  int n = blockIdx.x * 256 + threadIdx.x;
  if (n < NN) {
    float d = deg[n];
    dis[n] = d > 0.0f ? rsqrtf(d) : 0.0f;
  }
}

// Scan step 1: per-block sums of cnt.
__global__ __launch_bounds__(256) void k_scan1(const int* __restrict__ cnt,
                                               int* __restrict__ bsum) {
  __shared__ int s[4];
  int i = blockIdx.x * 256 + threadIdx.x;
  int v = (i < NN) ? cnt[i] : 0;
#pragma unroll
  for (int o = 32; o > 0; o >>= 1) v += __shfl_down(v, o, 64);
  if ((threadIdx.x & 63) == 0) s[threadIdx.x >> 6] = v;
  __syncthreads();
  if (threadIdx.x == 0) bsum[blockIdx.x] = s[0] + s[1] + s[2] + s[3];
}

// Scan step 2: exclusive scan of the 391 block sums (single block).
__global__ __launch_bounds__(512) void k_scan2(const int* __restrict__ bsum,
                                               int* __restrict__ boff) {
  __shared__ int s[512];
  int t = threadIdx.x;
  int v = (t < NBLK) ? bsum[t] : 0;
  s[t] = v;
  __syncthreads();
  for (int o = 1; o < 512; o <<= 1) {
    int a = (t >= o) ? s[t - o] : 0;
    __syncthreads();
    s[t] += a;
    __syncthreads();
  }
  if (t < NBLK) boff[t] = s[t] - v;  // exclusive
}

// Scan step 3: block-local exclusive scan + block offset -> rowptr, cursor.
__global__ __launch_bounds__(256) void k_scan3(const int* __restrict__ cnt,
                                               const int* __restrict__ boff,
                                               int* __restrict__ rowptr,
                                               int* __restrict__ cursor) {
  __shared__ int s[256];
  int t = threadIdx.x;
  int i = blockIdx.x * 256 + t;
  int v = (i < NN) ? cnt[i] : 0;
  s[t] = v;
  __syncthreads();
  for (int o = 1; o < 256; o <<= 1) {
    int a = (t >= o) ? s[t - o] : 0;
    __syncthreads();
    s[t] += a;
    __syncthreads();
  }
  int excl = s[t] - v + boff[blockIdx.x];
  if (i < NN) {
    rowptr[i] = excl;
    cursor[i] = excl;
  }
  if (i == NN) rowptr[NN] = NE;
}

// Reorder edges into CSR; fold in w_norm computation.
__global__ __launch_bounds__(256) void k_reorder(const int* __restrict__ row,
                                                 const int* __restrict__ col,
                                                 const float* __restrict__ ew,
                                                 const float* __restrict__ dis,
                                                 int* __restrict__ cursor,
                                                 int2* __restrict__ colw) {
  int e = blockIdx.x * 256 + threadIdx.x;
  if (e < NE) {
    int r = row[e];
    int c = col[e];
    float w = dis[r] * ew[e] * dis[c];
    int idx = atomicAdd(&cursor[r], 1);
    colw[idx] = make_int2(c, __float_as_int(w));
  }
}

struct GateParams {
  const float4* x4;    // [N][16]
  const float4* h4;    // [N][8]
  const float4* c4;    // [N][8]
  const int* rowptr;   // [N+1]
  const int2* colw;    // [E] {col, w_norm}
  const float4* W[4];  // [64][8] each
  const float* b[4];   // [32]
  const float4* T0[4]; // [32][8]
  const float4* T1[4]; // [32][8]
  const float* cb[4];  // [32]
  const float* Wlin;   // [32]
  const float* blin;   // [1]
  float* out;          // [N]
};

// Block = 256 threads, 64 nodes.
// Phase A: CSR gather-aggregate (8 threads/node, float4 each) -> sAgg in LDS.
// Phase B: dense gates matmul from LDS weights, 2 nodes/thread.
__global__ __launch_bounds__(256) void k_gates(GateParams p) {
  __shared__ float4 sW[4][64][8];   // 32 KB
  __shared__ float4 sT0[4][32][8];  // 16 KB
  __shared__ float4 sT1[4][32][8];  // 16 KB
  __shared__ float4 sAgg[64][9];    // 9 KB (pad 8->9 to break bank aliasing)
  __shared__ float sBias[4][32];
  __shared__ float sWlin[32];
  __shared__ float sBlin;

  const int t = threadIdx.x;
#pragma unroll
  for (int g = 0; g < 4; ++g) {
    float4* dW = &sW[g][0][0];
    for (int i = t; i < 512; i += 256) dW[i] = p.W[g][i];
    (&sT0[g][0][0])[t] = p.T0[g][t];
    (&sT1[g][0][0])[t] = p.T1[g][t];
  }
  if (t < 32) {
#pragma unroll
    for (int g = 0; g < 4; ++g) sBias[g][t] = p.b[g][t] + p.cb[g][t];
    sWlin[t] = p.Wlin[t];
  }
  if (t == 0) sBlin = p.blin[0];

  const int fg = t & 7;
  const int ng = t >> 3;
  const int nb0 = blockIdx.x * 64;

  // ---- Phase A: aggregation (no fp atomics; CSR gather) ----
#pragma unroll
  for (int pass = 0; pass < 2; ++pass) {
    int nl = ng + pass * 32;
    int n = nb0 + nl;
    float4 acc = make_float4(0.f, 0.f, 0.f, 0.f);
    if (n < NN) {
      int s0 = p.rowptr[n];
      int s1 = p.rowptr[n + 1];
      for (int j = s0; j < s1; ++j) {
        int2 cw = p.colw[j];
        float w = __int_as_float(cw.y);
        float4 hv = p.h4[cw.x * 8 + fg];
        acc.x = fmaf(w, hv.x, acc.x);
        acc.y = fmaf(w, hv.y, acc.y);
        acc.z = fmaf(w, hv.z, acc.z);
        acc.w = fmaf(w, hv.w, acc.w);
      }
    }
    sAgg[nl][fg] = acc;
  }
  __syncthreads();

  // ---- Phase B: gates matmul, 2 nodes/thread ----
  int nloc[2], nidx[2];
#pragma unroll
  for (int j = 0; j < 2; ++j) {
    nloc[j] = ng * 2 + j;
    int n = nb0 + nloc[j];
    nidx[j] = n < NN ? n : 0;
  }

  float4 acc[2][4];  // [node][gate]
#pragma unroll
  for (int j = 0; j < 2; ++j) {
#pragma unroll
    for (int g = 0; g < 4; ++g) {
      acc[j][g].x = sBias[g][fg * 4 + 0];
      acc[j][g].y = sBias[g][fg * 4 + 1];
      acc[j][g].z = sBias[g][fg * 4 + 2];
      acc[j][g].w = sBias[g][fg * 4 + 3];
    }
  }

  // x @ W (K = 64)
  for (int k4 = 0; k4 < 16; ++k4) {
    float4 xv[2];
#pragma unroll
    for (int j = 0; j < 2; ++j) xv[j] = p.x4[nidx[j] * 16 + k4];
#pragma unroll
    for (int kk = 0; kk < 4; ++kk) {
#pragma unroll
      for (int g = 0; g < 4; ++g) {
        float4 w = sW[g][k4 * 4 + kk][fg];
#pragma unroll
        for (int j = 0; j < 2; ++j) {
          float xs = (&xv[j].x)[kk];
          acc[j][g].x = fmaf(xs, w.x, acc[j][g].x);
          acc[j][g].y = fmaf(xs, w.y, acc[j][g].y);
          acc[j][g].z = fmaf(xs, w.z, acc[j][g].z);
          acc[j][g].w = fmaf(xs, w.w, acc[j][g].w);
        }
      }
    }
  }

  // h @ theta0 - agg @ theta1 (K = 32); agg comes from LDS
  for (int k4 = 0; k4 < 8; ++k4) {
    float4 hv[2], av[2];
#pragma unroll
    for (int j = 0; j < 2; ++j) {
      hv[j] = p.h4[nidx[j] * 8 + k4];
      av[j] = sAgg[nloc[j]][k4];
    }
#pragma unroll
    for (int kk = 0; kk < 4; ++kk) {
#pragma unroll
      for (int g = 0; g < 4; ++g) {
        float4 t0 = sT0[g][k4 * 4 + kk][fg];
        float4 t1 = sT1[g][k4 * 4 + kk][fg];
#pragma unroll
        for (int j = 0; j < 2; ++j) {
          float hs = (&hv[j].x)[kk];
          float as = -(&av[j].x)[kk];
          acc[j][g].x = fmaf(hs, t0.x, acc[j][g].x);
          acc[j][g].y = fmaf(hs, t0.y, acc[j][g].y);
          acc[j][g].z = fmaf(hs, t0.z, acc[j][g].z);
          acc[j][g].w = fmaf(hs, t0.w, acc[j][g].w);
          acc[j][g].x = fmaf(as, t1.x, acc[j][g].x);
          acc[j][g].y = fmaf(as, t1.y, acc[j][g].y);
          acc[j][g].z = fmaf(as, t1.z, acc[j][g].z);
          acc[j][g].w = fmaf(as, t1.w, acc[j][g].w);
        }
      }
    }
  }

  // Epilogue: gates, cell update, ReLU, dot W_lin, 8-lane reduce.
#pragma unroll
  for (int j = 0; j < 2; ++j) {
    float4 cv = p.c4[nidx[j] * 8 + fg];
    float partial = 0.0f;
#pragma unroll
    for (int kk = 0; kk < 4; ++kk) {
      float zi = (&acc[j][0].x)[kk];
      float zf = (&acc[j][1].x)[kk];
      float zc = (&acc[j][2].x)[kk];
      float zo = (&acc[j][3].x)[kk];
      float ccv = (&cv.x)[kk];
      float I = sigm(zi);
      float F = sigm(zf);
      float T = tanhf(zc);
      float O = sigm(zo);
      float C = fmaf(F, ccv, I * T);
      float H = O * tanhf(C);
      float r = fmaxf(H, 0.0f);
      partial = fmaf(r, sWlin[fg * 4 + kk], partial);
    }
    partial += __shfl_down(partial, 4, 8);
    partial += __shfl_down(partial, 2, 8);
    partial += __shfl_down(partial, 1, 8);
    int n = nb0 + nloc[j];
    if (fg == 0 && n < NN) p.out[n] = partial + sBlin;
  }
}

extern "C" void kernel_launch(void* const* d_in, const int* in_sizes, int n_in,
                              void* d_out, int out_size, void* d_ws, size_t ws_size,
                              hipStream_t stream) {
  const float* x = (const float*)d_in[0];
  const int* row = (const int*)d_in[1];
  const int* col = row + NE;
  const float* ew = (const float*)d_in[2];
  const float* h = (const float*)d_in[3];
  const float* c = (const float*)d_in[4];

  // Workspace layout (4-byte units). Total ~14.8 MB.
  float* ws = (float*)d_ws;
  float* deg = ws;                        // [0, 100000)
  int* cnt = (int*)(ws + NN);             // [100000, 200000)
  float* dis = ws + 2 * NN;               // [200000, 300000)
  int* rowptr = (int*)(ws + 3 * NN);      // [300000, 400001) (+pad)
  int* cursor = (int*)(ws + 3 * NN + NN + 4);       // [400004, 500004)
  int* bsum = (int*)(ws + 4 * NN + 4 + NN);         // [500004, 500516)
  int* boff = bsum + 512;                           // [500516, 501028)
  int2* colw = (int2*)(ws + 501032);                // 8B-aligned, 12.8 MB

  // zero deg + cnt (contiguous)
  hipMemsetAsync(deg, 0, 2 * NN * sizeof(float), stream);

  k_hist<<<NE / 256, 256, 0, stream>>>(row, ew, cnt, deg);
  k_dis<<<(NN + 255) / 256, 256, 0, stream>>>(deg, dis);
  k_scan1<<<NBLK, 256, 0, stream>>>(cnt, bsum);
  k_scan2<<<1, 512, 0, stream>>>(bsum, boff);
  k_scan3<<<NBLK, 256, 0, stream>>>(cnt, boff, rowptr, cursor);
  k_reorder<<<NE / 256, 256, 0, stream>>>(row, col, ew, dis, cursor, colw);

  GateParams p;
  p.x4 = (const float4*)x;
  p.h4 = (const float4*)h;
  p.c4 = (const float4*)c;
  p.rowptr = rowptr;
  p.colw = colw;
  for (int g = 0; g < 4; ++g) {
    p.W[g] = (const float4*)d_in[5 + 4 * g];
    p.b[g] = (const float*)d_in[6 + 4 * g];
    p.T0[g] = (const float4*)d_in[7 + 4 * g];
    p.T1[g] = p.T0[g] + 256;
    p.cb[g] = (const float*)d_in[8 + 4 * g];
  }
  p.Wlin = (const float*)d_in[21];
  p.blin = (const float*)d_in[22];
  p.out = (float*)d_out;

  k_gates<<<(NN + 63) / 64, 256, 0, stream>>>(p);
}

// Round 3
// 463.684 us; speedup vs baseline: 2.0929x; 1.1344x over previous
//
#include <hip/hip_runtime.h>
#include <math.h>

#define NN 100000
#define NE 1600000
#define NBLK 391  // ceil(NN/256)

__device__ __forceinline__ float sigm(float z) { return 1.0f / (1.0f + expf(-z)); }

// Phase 1: edge histogram (int count) + weighted degree, both atomically.
__global__ __launch_bounds__(256) void k_hist(const int* __restrict__ row,
                                              const float* __restrict__ ew,
                                              int* __restrict__ cnt,
                                              float* __restrict__ deg) {
  int e = blockIdx.x * 256 + threadIdx.x;
  if (e < NE) {
    int r = row[e];
    atomicAdd(&cnt[r], 1);
    unsafeAtomicAdd(&deg[r], ew[e]);
  }
}

__global__ __launch_bounds__(256) void k_dis(const float* __restrict__ deg,
                                             float* __restrict__ dis) {
  int n = blockIdx.x * 256 + threadIdx.x;
  if (n < NN) {
    float d = deg[n];
    dis[n] = d > 0.0f ? rsqrtf(d) : 0.0f;
  }
}

// Scan step 1: per-block sums of cnt.
__global__ __launch_bounds__(256) void k_scan1(const int* __restrict__ cnt,
                                               int* __restrict__ bsum) {
  __shared__ int s[4];
  int i = blockIdx.x * 256 + threadIdx.x;
  int v = (i < NN) ? cnt[i] : 0;
#pragma unroll
  for (int o = 32; o > 0; o >>= 1) v += __shfl_down(v, o, 64);
  if ((threadIdx.x & 63) == 0) s[threadIdx.x >> 6] = v;
  __syncthreads();
  if (threadIdx.x == 0) bsum[blockIdx.x] = s[0] + s[1] + s[2] + s[3];
}

// Scan step 2: exclusive scan of the 391 block sums (single block).
__global__ __launch_bounds__(512) void k_scan2(const int* __restrict__ bsum,
                                               int* __restrict__ boff) {
  __shared__ int s[512];
  int t = threadIdx.x;
  int v = (t < NBLK) ? bsum[t] : 0;
  s[t] = v;
  __syncthreads();
  for (int o = 1; o < 512; o <<= 1) {
    int a = (t >= o) ? s[t - o] : 0;
    __syncthreads();
    s[t] += a;
    __syncthreads();
  }
  if (t < NBLK) boff[t] = s[t] - v;  // exclusive
}

// Scan step 3: block-local exclusive scan + block offset -> rowptr, cursor.
__global__ __launch_bounds__(256) void k_scan3(const int* __restrict__ cnt,
                                               const int* __restrict__ boff,
                                               int* __restrict__ rowptr,
                                               int* __restrict__ cursor) {
  __shared__ int s[256];
  int t = threadIdx.x;
  int i = blockIdx.x * 256 + t;
  int v = (i < NN) ? cnt[i] : 0;
  s[t] = v;
  __syncthreads();
  for (int o = 1; o < 256; o <<= 1) {
    int a = (t >= o) ? s[t - o] : 0;
    __syncthreads();
    s[t] += a;
    __syncthreads();
  }
  int excl = s[t] - v + boff[blockIdx.x];
  if (i < NN) {
    rowptr[i] = excl;
    cursor[i] = excl;
  }
  if (i == NN) rowptr[NN] = NE;
}

// Reorder edges into CSR; fold in w_norm computation.
__global__ __launch_bounds__(256) void k_reorder(const int* __restrict__ row,
                                                 const int* __restrict__ col,
                                                 const float* __restrict__ ew,
                                                 const float* __restrict__ dis,
                                                 int* __restrict__ cursor,
                                                 int2* __restrict__ colw) {
  int e = blockIdx.x * 256 + threadIdx.x;
  if (e < NE) {
    int r = row[e];
    int c = col[e];
    float w = dis[r] * ew[e] * dis[c];
    int idx = atomicAdd(&cursor[r], 1);
    colw[idx] = make_int2(c, __float_as_int(w));
  }
}

// Aggregation: one WAVE per node. Lane = es*8 + fg: 8 edge-slots x 8 feature
// quads. Edges processed 8-at-a-time (avg degree 16 -> ~2 iters), then a
// 3-step shfl_xor reduction across edge-slots. No LDS, tiny VGPR -> max
// occupancy to hide the h[col] gather latency.
__global__ __launch_bounds__(256) void k_agg(const int* __restrict__ rowptr,
                                             const int2* __restrict__ colw,
                                             const float4* __restrict__ h4,
                                             float4* __restrict__ agg4) {
  int n = (blockIdx.x * 256 + threadIdx.x) >> 6;
  if (n >= NN) return;
  int lane = threadIdx.x & 63;
  int es = lane >> 3;
  int fg = lane & 7;
  int s0 = rowptr[n];
  int s1 = rowptr[n + 1];
  float4 acc = make_float4(0.f, 0.f, 0.f, 0.f);
  for (int j = s0 + es; j < s1; j += 8) {
    int2 cw = colw[j];
    float w = __int_as_float(cw.y);
    float4 hv = h4[cw.x * 8 + fg];
    acc.x = fmaf(w, hv.x, acc.x);
    acc.y = fmaf(w, hv.y, acc.y);
    acc.z = fmaf(w, hv.z, acc.z);
    acc.w = fmaf(w, hv.w, acc.w);
  }
#pragma unroll
  for (int o = 8; o < 64; o <<= 1) {
    acc.x += __shfl_xor(acc.x, o, 64);
    acc.y += __shfl_xor(acc.y, o, 64);
    acc.z += __shfl_xor(acc.z, o, 64);
    acc.w += __shfl_xor(acc.w, o, 64);
  }
  if (es == 0) agg4[n * 8 + fg] = acc;
}

struct GateParams {
  const float4* x4;    // [N][16]
  const float4* h4;    // [N][8]
  const float4* c4;    // [N][8]
  const int* rowptr;   // [N+1]
  const int2* colw;    // [E] {col, w_norm}
  const float4* agg4;  // [N][8] (split path)
  const float4* W[4];  // [64][8] each
  const float* b[4];   // [32]
  const float4* T0[4]; // [32][8]
  const float4* T1[4]; // [32][8]
  const float* cb[4];  // [32]
  const float* Wlin;   // [32]
  const float* blin;   // [1]
  float* out;          // [N]
};

// Block = 256 threads, 64 nodes.
// FUSED=true : Phase A CSR gather in-kernel (ws-constrained fallback).
// FUSED=false: agg read from global (k_agg ran first).
template <bool FUSED>
__global__ __launch_bounds__(256) void k_gates(GateParams p) {
  __shared__ float4 sW[4][64][8];   // 32 KB
  __shared__ float4 sT0[4][32][8];  // 16 KB
  __shared__ float4 sT1[4][32][8];  // 16 KB
  __shared__ float4 sAgg[64][9];    // 9 KB (pad 8->9)
  __shared__ float sBias[4][32];
  __shared__ float sWlin[32];
  __shared__ float sBlin;

  const int t = threadIdx.x;
#pragma unroll
  for (int g = 0; g < 4; ++g) {
    float4* dW = &sW[g][0][0];
    for (int i = t; i < 512; i += 256) dW[i] = p.W[g][i];
    (&sT0[g][0][0])[t] = p.T0[g][t];
    (&sT1[g][0][0])[t] = p.T1[g][t];
  }
  if (t < 32) {
#pragma unroll
    for (int g = 0; g < 4; ++g) sBias[g][t] = p.b[g][t] + p.cb[g][t];
    sWlin[t] = p.Wlin[t];
  }
  if (t == 0) sBlin = p.blin[0];

  const int fg = t & 7;
  const int ng = t >> 3;
  const int nb0 = blockIdx.x * 64;

  if (FUSED) {
#pragma unroll
    for (int pass = 0; pass < 2; ++pass) {
      int nl = ng + pass * 32;
      int n = nb0 + nl;
      float4 acc = make_float4(0.f, 0.f, 0.f, 0.f);
      if (n < NN) {
        int s0 = p.rowptr[n];
        int s1 = p.rowptr[n + 1];
        for (int j = s0; j < s1; ++j) {
          int2 cw = p.colw[j];
          float w = __int_as_float(cw.y);
          float4 hv = p.h4[cw.x * 8 + fg];
          acc.x = fmaf(w, hv.x, acc.x);
          acc.y = fmaf(w, hv.y, acc.y);
          acc.z = fmaf(w, hv.z, acc.z);
          acc.w = fmaf(w, hv.w, acc.w);
        }
      }
      sAgg[nl][fg] = acc;
    }
  }
  __syncthreads();

  // ---- dense gates matmul, 2 nodes/thread ----
  int nloc[2], nidx[2];
#pragma unroll
  for (int j = 0; j < 2; ++j) {
    nloc[j] = ng * 2 + j;
    int n = nb0 + nloc[j];
    nidx[j] = n < NN ? n : 0;
  }

  float4 acc[2][4];  // [node][gate]
#pragma unroll
  for (int j = 0; j < 2; ++j) {
#pragma unroll
    for (int g = 0; g < 4; ++g) {
      acc[j][g].x = sBias[g][fg * 4 + 0];
      acc[j][g].y = sBias[g][fg * 4 + 1];
      acc[j][g].z = sBias[g][fg * 4 + 2];
      acc[j][g].w = sBias[g][fg * 4 + 3];
    }
  }

  // x @ W (K = 64)
  for (int k4 = 0; k4 < 16; ++k4) {
    float4 xv[2];
#pragma unroll
    for (int j = 0; j < 2; ++j) xv[j] = p.x4[nidx[j] * 16 + k4];
#pragma unroll
    for (int kk = 0; kk < 4; ++kk) {
#pragma unroll
      for (int g = 0; g < 4; ++g) {
        float4 w = sW[g][k4 * 4 + kk][fg];
#pragma unroll
        for (int j = 0; j < 2; ++j) {
          float xs = (&xv[j].x)[kk];
          acc[j][g].x = fmaf(xs, w.x, acc[j][g].x);
          acc[j][g].y = fmaf(xs, w.y, acc[j][g].y);
          acc[j][g].z = fmaf(xs, w.z, acc[j][g].z);
          acc[j][g].w = fmaf(xs, w.w, acc[j][g].w);
        }
      }
    }
  }

  // h @ theta0 - agg @ theta1 (K = 32)
  for (int k4 = 0; k4 < 8; ++k4) {
    float4 hv[2], av[2];
#pragma unroll
    for (int j = 0; j < 2; ++j) {
      hv[j] = p.h4[nidx[j] * 8 + k4];
      av[j] = FUSED ? sAgg[nloc[j]][k4] : p.agg4[nidx[j] * 8 + k4];
    }
#pragma unroll
    for (int kk = 0; kk < 4; ++kk) {
#pragma unroll
      for (int g = 0; g < 4; ++g) {
        float4 t0 = sT0[g][k4 * 4 + kk][fg];
        float4 t1 = sT1[g][k4 * 4 + kk][fg];
#pragma unroll
        for (int j = 0; j < 2; ++j) {
          float hs = (&hv[j].x)[kk];
          float as = -(&av[j].x)[kk];
          acc[j][g].x = fmaf(hs, t0.x, acc[j][g].x);
          acc[j][g].y = fmaf(hs, t0.y, acc[j][g].y);
          acc[j][g].z = fmaf(hs, t0.z, acc[j][g].z);
          acc[j][g].w = fmaf(hs, t0.w, acc[j][g].w);
          acc[j][g].x = fmaf(as, t1.x, acc[j][g].x);
          acc[j][g].y = fmaf(as, t1.y, acc[j][g].y);
          acc[j][g].z = fmaf(as, t1.z, acc[j][g].z);
          acc[j][g].w = fmaf(as, t1.w, acc[j][g].w);
        }
      }
    }
  }

  // Epilogue: gates, cell update, ReLU, dot W_lin, 8-lane reduce.
#pragma unroll
  for (int j = 0; j < 2; ++j) {
    float4 cv = p.c4[nidx[j] * 8 + fg];
    float partial = 0.0f;
#pragma unroll
    for (int kk = 0; kk < 4; ++kk) {
      float zi = (&acc[j][0].x)[kk];
      float zf = (&acc[j][1].x)[kk];
      float zc = (&acc[j][2].x)[kk];
      float zo = (&acc[j][3].x)[kk];
      float ccv = (&cv.x)[kk];
      float I = sigm(zi);
      float F = sigm(zf);
      float T = tanhf(zc);
      float O = sigm(zo);
      float C = fmaf(F, ccv, I * T);
      float H = O * tanhf(C);
      float r = fmaxf(H, 0.0f);
      partial = fmaf(r, sWlin[fg * 4 + kk], partial);
    }
    partial += __shfl_down(partial, 4, 8);
    partial += __shfl_down(partial, 2, 8);
    partial += __shfl_down(partial, 1, 8);
    int n = nb0 + nloc[j];
    if (fg == 0 && n < NN) p.out[n] = partial + sBlin;
  }
}

extern "C" void kernel_launch(void* const* d_in, const int* in_sizes, int n_in,
                              void* d_out, int out_size, void* d_ws, size_t ws_size,
                              hipStream_t stream) {
  const float* x = (const float*)d_in[0];
  const int* row = (const int*)d_in[1];
  const int* col = row + NE;
  const float* ew = (const float*)d_in[2];
  const float* h = (const float*)d_in[3];
  const float* c = (const float*)d_in[4];

  // Workspace layout (4-byte units).
  float* ws = (float*)d_ws;
  float* deg = ws;                        // [0, 1e5)
  int* cnt = (int*)(ws + NN);             // [1e5, 2e5)
  float* dis = ws + 2 * NN;               // [2e5, 3e5)
  int* rowptr = (int*)(ws + 3 * NN);      // [3e5, 4e5+1)
  int* cursor = (int*)(ws + 4 * NN + 4);  // [4e5+4, 5e5+4)
  int* bsum = (int*)(ws + 5 * NN + 4);
  int* boff = bsum + 512;
  int2* colw = (int2*)(ws + 501032);      // 12.8 MB, 8B-aligned
  float* agg = ws + 501032 + 2 * NE;      // 12.8 MB, 16B-aligned
  const size_t need = (size_t)(501032 + 2 * NE + 32 * NN) * 4;  // ~27.6 MB
  const bool split = ws_size >= need;

  // zero deg + cnt (contiguous)
  hipMemsetAsync(deg, 0, 2 * NN * sizeof(float), stream);

  k_hist<<<NE / 256, 256, 0, stream>>>(row, ew, cnt, deg);
  k_dis<<<(NN + 255) / 256, 256, 0, stream>>>(deg, dis);
  k_scan1<<<NBLK, 256, 0, stream>>>(cnt, bsum);
  k_scan2<<<1, 512, 0, stream>>>(bsum, boff);
  k_scan3<<<NBLK, 256, 0, stream>>>(cnt, boff, rowptr, cursor);
  k_reorder<<<NE / 256, 256, 0, stream>>>(row, col, ew, dis, cursor, colw);

  GateParams p;
  p.x4 = (const float4*)x;
  p.h4 = (const float4*)h;
  p.c4 = (const float4*)c;
  p.rowptr = rowptr;
  p.colw = colw;
  p.agg4 = (const float4*)agg;
  for (int g = 0; g < 4; ++g) {
    p.W[g] = (const float4*)d_in[5 + 4 * g];
    p.b[g] = (const float*)d_in[6 + 4 * g];
    p.T0[g] = (const float4*)d_in[7 + 4 * g];
    p.T1[g] = p.T0[g] + 256;
    p.cb[g] = (const float*)d_in[8 + 4 * g];
  }
  p.Wlin = (const float*)d_in[21];
  p.blin = (const float*)d_in[22];
  p.out = (float*)d_out;

  if (split) {
    k_agg<<<(NN + 3) / 4, 256, 0, stream>>>(rowptr, colw, (const float4*)h,
                                            (float4*)agg);
    k_gates<false><<<(NN + 63) / 64, 256, 0, stream>>>(p);
  } else {
    k_gates<true><<<(NN + 63) / 64, 256, 0, stream>>>(p);
  }
}

// Round 4
// 344.531 us; speedup vs baseline: 2.8168x; 1.3458x over previous
//
#include <hip/hip_runtime.h>
#include <math.h>

#define NN 100000
#define NE 1600000
#define NBLK 391  // ceil(NN/256)

#define FIXSCALE 67108864.0f        // 2^26
#define FIXMASK 0xFFFFFFFFFFFULL    // low 44 bits

__device__ __forceinline__ float sigm(float z) { return 1.0f / (1.0f + expf(-z)); }

// ONE packed 64-bit atomic per edge: high 20 bits count, low 44 bits
// fixed-point sum of ew. Returned old value gives this edge's rank within
// its row (stored for atomic-free reorder later).
__global__ __launch_bounds__(256) void k_hist(const int* __restrict__ row,
                                              const float* __restrict__ ew,
                                              unsigned long long* __restrict__ packed,
                                              unsigned short* __restrict__ rank16) {
  int e = blockIdx.x * 256 + threadIdx.x;
  if (e < NE) {
    int r = row[e];
    unsigned long long val =
        (1ULL << 44) | (unsigned long long)(unsigned)(ew[e] * FIXSCALE + 0.5f);
    unsigned long long old = atomicAdd(&packed[r], val);
    rank16[e] = (unsigned short)(old >> 44);
  }
}

// Scan step 1: per-block sums of counts.
__global__ __launch_bounds__(256) void k_scan1(const unsigned long long* __restrict__ packed,
                                               int* __restrict__ bsum) {
  __shared__ int s[4];
  int i = blockIdx.x * 256 + threadIdx.x;
  int v = (i < NN) ? (int)(packed[i] >> 44) : 0;
#pragma unroll
  for (int o = 32; o > 0; o >>= 1) v += __shfl_down(v, o, 64);
  if ((threadIdx.x & 63) == 0) s[threadIdx.x >> 6] = v;
  __syncthreads();
  if (threadIdx.x == 0) bsum[blockIdx.x] = s[0] + s[1] + s[2] + s[3];
}

// Scan step 2: exclusive scan of the 391 block sums (single block).
__global__ __launch_bounds__(512) void k_scan2(const int* __restrict__ bsum,
                                               int* __restrict__ boff) {
  __shared__ int s[512];
  int t = threadIdx.x;
  int v = (t < NBLK) ? bsum[t] : 0;
  s[t] = v;
  __syncthreads();
  for (int o = 1; o < 512; o <<= 1) {
    int a = (t >= o) ? s[t - o] : 0;
    __syncthreads();
    s[t] += a;
    __syncthreads();
  }
  if (t < NBLK) boff[t] = s[t] - v;  // exclusive
}

// Scan step 3: block-local exclusive scan + block offset -> rowptr.
// Also folds in dis = rsqrt(deg) from the packed fixed-point degree.
__global__ __launch_bounds__(256) void k_scan3(const unsigned long long* __restrict__ packed,
                                               const int* __restrict__ boff,
                                               int* __restrict__ rowptr,
                                               float* __restrict__ dis) {
  __shared__ int s[256];
  int t = threadIdx.x;
  int i = blockIdx.x * 256 + t;
  unsigned long long pk = (i < NN) ? packed[i] : 0ULL;
  int v = (int)(pk >> 44);
  s[t] = v;
  __syncthreads();
  for (int o = 1; o < 256; o <<= 1) {
    int a = (t >= o) ? s[t - o] : 0;
    __syncthreads();
    s[t] += a;
    __syncthreads();
  }
  if (i < NN) {
    rowptr[i] = s[t] - v + boff[blockIdx.x];
    unsigned long long fx = pk & FIXMASK;
    float deg = (float)((double)fx * (1.0 / (double)FIXSCALE));
    dis[i] = fx > 0 ? rsqrtf(deg) : 0.0f;
  }
  if (i == NN) rowptr[NN] = NE;
}

// Reorder edges into CSR — NO atomics (rank precomputed in k_hist).
__global__ __launch_bounds__(256) void k_reorder(const int* __restrict__ row,
                                                 const int* __restrict__ col,
                                                 const float* __restrict__ ew,
                                                 const unsigned short* __restrict__ rank16,
                                                 const int* __restrict__ rowptr,
                                                 const float* __restrict__ dis,
                                                 int2* __restrict__ colw) {
  int e = blockIdx.x * 256 + threadIdx.x;
  if (e < NE) {
    int r = row[e];
    int c = col[e];
    float w = dis[r] * ew[e] * dis[c];
    int idx = rowptr[r] + (int)rank16[e];
    colw[idx] = make_int2(c, __float_as_int(w));
  }
}

// Aggregation: one WAVE per node. Lane = es*8 + fg: 8 edge-slots x 8 feature
// quads. No LDS, tiny VGPR -> max occupancy hides the h[col] gather latency.
__global__ __launch_bounds__(256) void k_agg(const int* __restrict__ rowptr,
                                             const int2* __restrict__ colw,
                                             const float4* __restrict__ h4,
                                             float4* __restrict__ agg4) {
  int n = (blockIdx.x * 256 + threadIdx.x) >> 6;
  if (n >= NN) return;
  int lane = threadIdx.x & 63;
  int es = lane >> 3;
  int fg = lane & 7;
  int s0 = rowptr[n];
  int s1 = rowptr[n + 1];
  float4 acc = make_float4(0.f, 0.f, 0.f, 0.f);
  for (int j = s0 + es; j < s1; j += 8) {
    int2 cw = colw[j];
    float w = __int_as_float(cw.y);
    float4 hv = h4[cw.x * 8 + fg];
    acc.x = fmaf(w, hv.x, acc.x);
    acc.y = fmaf(w, hv.y, acc.y);
    acc.z = fmaf(w, hv.z, acc.z);
    acc.w = fmaf(w, hv.w, acc.w);
  }
#pragma unroll
  for (int o = 8; o < 64; o <<= 1) {
    acc.x += __shfl_xor(acc.x, o, 64);
    acc.y += __shfl_xor(acc.y, o, 64);
    acc.z += __shfl_xor(acc.z, o, 64);
    acc.w += __shfl_xor(acc.w, o, 64);
  }
  if (es == 0) agg4[n * 8 + fg] = acc;
}

struct GateParams {
  const float4* x4;    // [N][16]
  const float4* h4;    // [N][8]
  const float4* c4;    // [N][8]
  const int* rowptr;   // [N+1]
  const int2* colw;    // [E] {col, w_norm}
  const float4* agg4;  // [N][8] (split path)
  const float4* W[4];  // [64][8] each
  const float* b[4];   // [32]
  const float4* T0[4]; // [32][8]
  const float4* T1[4]; // [32][8]
  const float* cb[4];  // [32]
  const float* Wlin;   // [32]
  const float* blin;   // [1]
  float* out;          // [N]
};

// Block = 256 threads, 64 nodes.
// FUSED=true : Phase A CSR gather in-kernel (ws-constrained fallback).
// FUSED=false: agg read from global (k_agg ran first).
template <bool FUSED>
__global__ __launch_bounds__(256) void k_gates(GateParams p) {
  __shared__ float4 sW[4][64][8];   // 32 KB
  __shared__ float4 sT0[4][32][8];  // 16 KB
  __shared__ float4 sT1[4][32][8];  // 16 KB
  __shared__ float4 sAgg[64][9];    // 9 KB (pad 8->9)
  __shared__ float sBias[4][32];
  __shared__ float sWlin[32];
  __shared__ float sBlin;

  const int t = threadIdx.x;
#pragma unroll
  for (int g = 0; g < 4; ++g) {
    float4* dW = &sW[g][0][0];
    for (int i = t; i < 512; i += 256) dW[i] = p.W[g][i];
    (&sT0[g][0][0])[t] = p.T0[g][t];
    (&sT1[g][0][0])[t] = p.T1[g][t];
  }
  if (t < 32) {
#pragma unroll
    for (int g = 0; g < 4; ++g) sBias[g][t] = p.b[g][t] + p.cb[g][t];
    sWlin[t] = p.Wlin[t];
  }
  if (t == 0) sBlin = p.blin[0];

  const int fg = t & 7;
  const int ng = t >> 3;
  const int nb0 = blockIdx.x * 64;

  if (FUSED) {
#pragma unroll
    for (int pass = 0; pass < 2; ++pass) {
      int nl = ng + pass * 32;
      int n = nb0 + nl;
      float4 acc = make_float4(0.f, 0.f, 0.f, 0.f);
      if (n < NN) {
        int s0 = p.rowptr[n];
        int s1 = p.rowptr[n + 1];
        for (int j = s0; j < s1; ++j) {
          int2 cw = p.colw[j];
          float w = __int_as_float(cw.y);
          float4 hv = p.h4[cw.x * 8 + fg];
          acc.x = fmaf(w, hv.x, acc.x);
          acc.y = fmaf(w, hv.y, acc.y);
          acc.z = fmaf(w, hv.z, acc.z);
          acc.w = fmaf(w, hv.w, acc.w);
        }
      }
      sAgg[nl][fg] = acc;
    }
  }
  __syncthreads();

  // ---- dense gates matmul, 2 nodes/thread ----
  int nloc[2], nidx[2];
#pragma unroll
  for (int j = 0; j < 2; ++j) {
    nloc[j] = ng * 2 + j;
    int n = nb0 + nloc[j];
    nidx[j] = n < NN ? n : 0;
  }

  float4 acc[2][4];  // [node][gate]
#pragma unroll
  for (int j = 0; j < 2; ++j) {
#pragma unroll
    for (int g = 0; g < 4; ++g) {
      acc[j][g].x = sBias[g][fg * 4 + 0];
      acc[j][g].y = sBias[g][fg * 4 + 1];
      acc[j][g].z = sBias[g][fg * 4 + 2];
      acc[j][g].w = sBias[g][fg * 4 + 3];
    }
  }

  // x @ W (K = 64)
  for (int k4 = 0; k4 < 16; ++k4) {
    float4 xv[2];
#pragma unroll
    for (int j = 0; j < 2; ++j) xv[j] = p.x4[nidx[j] * 16 + k4];
#pragma unroll
    for (int kk = 0; kk < 4; ++kk) {
#pragma unroll
      for (int g = 0; g < 4; ++g) {
        float4 w = sW[g][k4 * 4 + kk][fg];
#pragma unroll
        for (int j = 0; j < 2; ++j) {
          float xs = (&xv[j].x)[kk];
          acc[j][g].x = fmaf(xs, w.x, acc[j][g].x);
          acc[j][g].y = fmaf(xs, w.y, acc[j][g].y);
          acc[j][g].z = fmaf(xs, w.z, acc[j][g].z);
          acc[j][g].w = fmaf(xs, w.w, acc[j][g].w);
        }
      }
    }
  }

  // h @ theta0 - agg @ theta1 (K = 32)
  for (int k4 = 0; k4 < 8; ++k4) {
    float4 hv[2], av[2];
#pragma unroll
    for (int j = 0; j < 2; ++j) {
      hv[j] = p.h4[nidx[j] * 8 + k4];
      av[j] = FUSED ? sAgg[nloc[j]][k4] : p.agg4[nidx[j] * 8 + k4];
    }
#pragma unroll
    for (int kk = 0; kk < 4; ++kk) {
#pragma unroll
      for (int g = 0; g < 4; ++g) {
        float4 t0 = sT0[g][k4 * 4 + kk][fg];
        float4 t1 = sT1[g][k4 * 4 + kk][fg];
#pragma unroll
        for (int j = 0; j < 2; ++j) {
          float hs = (&hv[j].x)[kk];
          float as = -(&av[j].x)[kk];
          acc[j][g].x = fmaf(hs, t0.x, acc[j][g].x);
          acc[j][g].y = fmaf(hs, t0.y, acc[j][g].y);
          acc[j][g].z = fmaf(hs, t0.z, acc[j][g].z);
          acc[j][g].w = fmaf(hs, t0.w, acc[j][g].w);
          acc[j][g].x = fmaf(as, t1.x, acc[j][g].x);
          acc[j][g].y = fmaf(as, t1.y, acc[j][g].y);
          acc[j][g].z = fmaf(as, t1.z, acc[j][g].z);
          acc[j][g].w = fmaf(as, t1.w, acc[j][g].w);
        }
      }
    }
  }

  // Epilogue: gates, cell update, ReLU, dot W_lin, 8-lane reduce.
#pragma unroll
  for (int j = 0; j < 2; ++j) {
    float4 cv = p.c4[nidx[j] * 8 + fg];
    float partial = 0.0f;
#pragma unroll
    for (int kk = 0; kk < 4; ++kk) {
      float zi = (&acc[j][0].x)[kk];
      float zf = (&acc[j][1].x)[kk];
      float zc = (&acc[j][2].x)[kk];
      float zo = (&acc[j][3].x)[kk];
      float ccv = (&cv.x)[kk];
      float I = sigm(zi);
      float F = sigm(zf);
      float T = tanhf(zc);
      float O = sigm(zo);
      float C = fmaf(F, ccv, I * T);
      float H = O * tanhf(C);
      float r = fmaxf(H, 0.0f);
      partial = fmaf(r, sWlin[fg * 4 + kk], partial);
    }
    partial += __shfl_down(partial, 4, 8);
    partial += __shfl_down(partial, 2, 8);
    partial += __shfl_down(partial, 1, 8);
    int n = nb0 + nloc[j];
    if (fg == 0 && n < NN) p.out[n] = partial + sBlin;
  }
}

extern "C" void kernel_launch(void* const* d_in, const int* in_sizes, int n_in,
                              void* d_out, int out_size, void* d_ws, size_t ws_size,
                              hipStream_t stream) {
  const float* x = (const float*)d_in[0];
  const int* row = (const int*)d_in[1];
  const int* col = row + NE;
  const float* ew = (const float*)d_in[2];
  const float* h = (const float*)d_in[3];
  const float* c = (const float*)d_in[4];

  // Workspace layout (4-byte units).
  float* ws = (float*)d_ws;
  unsigned long long* packed = (unsigned long long*)ws;     // [0, 2e5) : uint64[NN]
  float* dis = ws + 2 * NN;                                 // [2e5, 3e5)
  int* rowptr = (int*)(ws + 3 * NN);                        // [3e5, 4e5+1)
  unsigned short* rank16 = (unsigned short*)(ws + 400004);  // 3.2 MB: [400004, 1200004)
  int* bsum = (int*)(ws + 1200004);
  int* boff = bsum + 512;
  int2* colw = (int2*)(ws + 1201032);                       // 12.8 MB, 8B-aligned
  float* agg = ws + 1201032 + 2 * NE;                       // 12.8 MB, 16B-aligned
  const size_t need = (size_t)(1201032 + 2 * NE + 32 * NN) * 4;  // ~30.4 MB
  const bool split = ws_size >= need;

  hipMemsetAsync(packed, 0, NN * sizeof(unsigned long long), stream);

  k_hist<<<NE / 256, 256, 0, stream>>>(row, ew, packed, rank16);
  k_scan1<<<NBLK, 256, 0, stream>>>(packed, bsum);
  k_scan2<<<1, 512, 0, stream>>>(bsum, boff);
  k_scan3<<<NBLK, 256, 0, stream>>>(packed, boff, rowptr, dis);
  k_reorder<<<NE / 256, 256, 0, stream>>>(row, col, ew, rank16, rowptr, dis, colw);

  GateParams p;
  p.x4 = (const float4*)x;
  p.h4 = (const float4*)h;
  p.c4 = (const float4*)c;
  p.rowptr = rowptr;
  p.colw = colw;
  p.agg4 = (const float4*)agg;
  for (int g = 0; g < 4; ++g) {
    p.W[g] = (const float4*)d_in[5 + 4 * g];
    p.b[g] = (const float*)d_in[6 + 4 * g];
    p.T0[g] = (const float4*)d_in[7 + 4 * g];
    p.T1[g] = p.T0[g] + 256;
    p.cb[g] = (const float*)d_in[8 + 4 * g];
  }
  p.Wlin = (const float*)d_in[21];
  p.blin = (const float*)d_in[22];
  p.out = (float*)d_out;

  if (split) {
    k_agg<<<(NN + 3) / 4, 256, 0, stream>>>(rowptr, colw, (const float4*)h,
                                            (float4*)agg);
    k_gates<false><<<(NN + 63) / 64, 256, 0, stream>>>(p);
  } else {
    k_gates<true><<<(NN + 63) / 64, 256, 0, stream>>>(p);
  }
}

// Round 6
// 319.494 us; speedup vs baseline: 3.0375x; 1.0784x over previous
//
#include <hip/hip_runtime.h>
#include <math.h>

#define NN 100000
#define NE 1600000
#define NBLK 391  // ceil(NN/256)

#define FIXSCALE 67108864.0f        // 2^26
#define FIXMASK 0xFFFFFFFFFFFULL    // low 44 bits

typedef __attribute__((ext_vector_type(8))) short bf16x8;
typedef __attribute__((ext_vector_type(4))) float f32x4;

#define MFMA(A, B, C) __builtin_amdgcn_mfma_f32_16x16x32_bf16(A, B, C, 0, 0, 0)

__device__ __forceinline__ float sigm(float z) { return 1.0f / (1.0f + expf(-z)); }

// Split fp32 into two truncated bf16 halves: v ~= hi + lo, |err| <~ 2^-16 |v|.
__device__ __forceinline__ void split1(float v, unsigned short* hi, unsigned short* lo) {
  unsigned u = __float_as_uint(v);
  *hi = (unsigned short)(u >> 16);
  float hf = __uint_as_float(u & 0xFFFF0000u);
  float lf = v - hf;
  *lo = (unsigned short)(__float_as_uint(lf) >> 16);
}

__device__ __forceinline__ void split8(const float* f, bf16x8* hi, bf16x8* lo) {
#pragma unroll
  for (int j = 0; j < 8; ++j) {
    unsigned short h, l;
    split1(f[j], &h, &l);
    (*hi)[j] = (short)h;
    (*lo)[j] = (short)l;
  }
}

__device__ __forceinline__ bf16x8 as_bf16x8(uint4 q) {
  union { uint4 q; bf16x8 v; } u;
  u.q = q;
  return u.v;
}

__device__ __forceinline__ void load8(const float4* p, int idx4, float* f) {
  float4 a = p[idx4];
  float4 b = p[idx4 + 1];
  f[0] = a.x; f[1] = a.y; f[2] = a.z; f[3] = a.w;
  f[4] = b.x; f[5] = b.y; f[6] = b.z; f[7] = b.w;
}

// ONE packed 64-bit atomic per edge: high 20 bits count, low 44 bits
// fixed-point sum of ew. Returned old value gives this edge's rank within
// its row (stored for atomic-free reorder later).
__global__ __launch_bounds__(256) void k_hist(const int* __restrict__ row,
                                              const float* __restrict__ ew,
                                              unsigned long long* __restrict__ packed,
                                              unsigned short* __restrict__ rank16) {
  int e = blockIdx.x * 256 + threadIdx.x;
  if (e < NE) {
    int r = row[e];
    unsigned long long val =
        (1ULL << 44) | (unsigned long long)(unsigned)(ew[e] * FIXSCALE + 0.5f);
    unsigned long long old = atomicAdd(&packed[r], val);
    rank16[e] = (unsigned short)(old >> 44);
  }
}

// Scan step 1: per-block sums of counts.
__global__ __launch_bounds__(256) void k_scan1(const unsigned long long* __restrict__ packed,
                                               int* __restrict__ bsum) {
  __shared__ int s[4];
  int i = blockIdx.x * 256 + threadIdx.x;
  int v = (i < NN) ? (int)(packed[i] >> 44) : 0;
#pragma unroll
  for (int o = 32; o > 0; o >>= 1) v += __shfl_down(v, o, 64);
  if ((threadIdx.x & 63) == 0) s[threadIdx.x >> 6] = v;
  __syncthreads();
  if (threadIdx.x == 0) bsum[blockIdx.x] = s[0] + s[1] + s[2] + s[3];
}

// Scan step 2: exclusive scan of the 391 block sums (single block).
__global__ __launch_bounds__(512) void k_scan2(const int* __restrict__ bsum,
                                               int* __restrict__ boff) {
  __shared__ int s[512];
  int t = threadIdx.x;
  int v = (t < NBLK) ? bsum[t] : 0;
  s[t] = v;
  __syncthreads();
  for (int o = 1; o < 512; o <<= 1) {
    int a = (t >= o) ? s[t - o] : 0;
    __syncthreads();
    s[t] += a;
    __syncthreads();
  }
  if (t < NBLK) boff[t] = s[t] - v;  // exclusive
}

// Scan step 3: block-local exclusive scan + block offset -> rowptr.
// Also folds in dis = rsqrt(deg) from the packed fixed-point degree.
__global__ __launch_bounds__(256) void k_scan3(const unsigned long long* __restrict__ packed,
                                               const int* __restrict__ boff,
                                               int* __restrict__ rowptr,
                                               float* __restrict__ dis) {
  __shared__ int s[256];
  int t = threadIdx.x;
  int i = blockIdx.x * 256 + t;
  unsigned long long pk = (i < NN) ? packed[i] : 0ULL;
  int v = (int)(pk >> 44);
  s[t] = v;
  __syncthreads();
  for (int o = 1; o < 256; o <<= 1) {
    int a = (t >= o) ? s[t - o] : 0;
    __syncthreads();
    s[t] += a;
    __syncthreads();
  }
  if (i < NN) {
    rowptr[i] = s[t] - v + boff[blockIdx.x];
    unsigned long long fx = pk & FIXMASK;
    float deg = (float)((double)fx * (1.0 / (double)FIXSCALE));
    dis[i] = fx > 0 ? rsqrtf(deg) : 0.0f;
  }
  if (i == NN) rowptr[NN] = NE;
}

// Reorder edges into CSR — NO atomics (rank precomputed in k_hist).
__global__ __launch_bounds__(256) void k_reorder(const int* __restrict__ row,
                                                 const int* __restrict__ col,
                                                 const float* __restrict__ ew,
                                                 const unsigned short* __restrict__ rank16,
                                                 const int* __restrict__ rowptr,
                                                 const float* __restrict__ dis,
                                                 int2* __restrict__ colw) {
  int e = blockIdx.x * 256 + threadIdx.x;
  if (e < NE) {
    int r = row[e];
    int c = col[e];
    float w = dis[r] * ew[e] * dis[c];
    int idx = rowptr[r] + (int)rank16[e];
    colw[idx] = make_int2(c, __float_as_int(w));
  }
}

// Aggregation: one WAVE per node. Lane = es*8 + fg: 8 edge-slots x 8 feature
// quads. No LDS, tiny VGPR -> max occupancy hides the h[col] gather latency.
__global__ __launch_bounds__(256) void k_agg(const int* __restrict__ rowptr,
                                             const int2* __restrict__ colw,
                                             const float4* __restrict__ h4,
                                             float4* __restrict__ agg4) {
  int n = (blockIdx.x * 256 + threadIdx.x) >> 6;
  if (n >= NN) return;
  int lane = threadIdx.x & 63;
  int es = lane >> 3;
  int fg = lane & 7;
  int s0 = rowptr[n];
  int s1 = rowptr[n + 1];
  float4 acc = make_float4(0.f, 0.f, 0.f, 0.f);
  for (int j = s0 + es; j < s1; j += 8) {
    int2 cw = colw[j];
    float w = __int_as_float(cw.y);
    float4 hv = h4[cw.x * 8 + fg];
    acc.x = fmaf(w, hv.x, acc.x);
    acc.y = fmaf(w, hv.y, acc.y);
    acc.z = fmaf(w, hv.z, acc.z);
    acc.w = fmaf(w, hv.w, acc.w);
  }
#pragma unroll
  for (int o = 8; o < 64; o <<= 1) {
    acc.x += __shfl_xor(acc.x, o, 64);
    acc.y += __shfl_xor(acc.y, o, 64);
    acc.z += __shfl_xor(acc.z, o, 64);
    acc.w += __shfl_xor(acc.w, o, 64);
  }
  if (es == 0) agg4[n * 8 + fg] = acc;
}

// ---- MFMA dense path ----
// Weight B-fragments, tiles T = 0..31, each [64 lanes][8 bf16]:
//   T = kt*8+nt (kt<2)  : x-W   (K=64, cols = 4 gates x 32 concatenated)
//   T = 16+nt           : theta0 (K=32)
//   T = 24+nt           : theta1 (K=32)
// Fragment layout: B[k = quad*8+j][n = nt*16 + (lane&15)].
struct PrepParams {
  const float* W[4];
  const float* T0[4];
  const float* T1[4];
  const float* b[4];
  const float* cb[4];
  uint4* fh;
  uint4* fl;
  float* bias;  // [128] b+cb concatenated per gate
};

__global__ __launch_bounds__(256) void k_prep(PrepParams pp) {
  int idx = blockIdx.x * 256 + threadIdx.x;  // entry = T*64 + lane, 2048 total
  if (idx < 2048) {
    int T = idx >> 6;
    int lane = idx & 63;
    int ncol = ((T & 7) * 16) + (lane & 15);
    int g = ncol >> 5;
    int c = ncol & 31;
    int kq = (lane >> 4) * 8;
    const float* mat;
    int kbase;
    if (T < 16) { mat = pp.W[g]; kbase = (T >> 3) * 32 + kq; }
    else if (T < 24) { mat = pp.T0[g]; kbase = kq; }
    else { mat = pp.T1[g]; kbase = kq; }
    unsigned hw[4], lw[4];
#pragma unroll
    for (int jj = 0; jj < 4; ++jj) {
      unsigned short h0, l0, h1, l1;
      split1(mat[(kbase + 2 * jj) * 32 + c], &h0, &l0);
      split1(mat[(kbase + 2 * jj + 1) * 32 + c], &h1, &l1);
      hw[jj] = (unsigned)h0 | ((unsigned)h1 << 16);
      lw[jj] = (unsigned)l0 | ((unsigned)l1 << 16);
    }
    pp.fh[idx] = make_uint4(hw[0], hw[1], hw[2], hw[3]);
    pp.fl[idx] = make_uint4(lw[0], lw[1], lw[2], lw[3]);
  }
  if (blockIdx.x == 0 && threadIdx.x < 128) {
    int g = threadIdx.x >> 5;
    int c = threadIdx.x & 31;
    pp.bias[threadIdx.x] = pp.b[g][c] + pp.cb[g][c];
  }
}

struct GmmParams {
  const float4* x4;    // [N][16]
  const float4* h4;    // [N][8]
  const float4* agg4;  // [N][8]
  const float* cst;    // [N][32]
  const uint4* fh;
  const uint4* fl;
  const float* bias;   // [128]
  const float* wlin;   // [32]
  const float* blin;   // [1]
  float* out;          // [N]
};

// One wave per 16 nodes; D-tile 16 nodes x 128 cols (4 gates x 32).
// A (x/h/-agg) loaded fp32, split to bf16 hi/lo in-register.
// A layout: A[m=lane&15][k=quad*8+j]; C/D: col=lane&15, row=quad*4+reg.
__global__ __launch_bounds__(256) void k_gmm(GmmParams p) {
  const int lane = threadIdx.x & 63;
  const int wv = threadIdx.x >> 6;
  const int m0 = blockIdx.x * 64 + wv * 16;
  const int mr = lane & 15;
  const int quad = lane >> 4;
  int m = m0 + mr;
  if (m >= NN) m = NN - 1;

  bf16x8 xh[2], xl[2], hh, hl, gh, gl;
  float f[8];
#pragma unroll
  for (int kt = 0; kt < 2; ++kt) {
    load8(p.x4, (m * 64 + kt * 32 + quad * 8) >> 2, f);
    split8(f, &xh[kt], &xl[kt]);
  }
  load8(p.h4, (m * 32 + quad * 8) >> 2, f);
  split8(f, &hh, &hl);
  load8(p.agg4, (m * 32 + quad * 8) >> 2, f);
#pragma unroll
  for (int j = 0; j < 8; ++j) f[j] = -f[j];  // subtract agg@theta1
  split8(f, &gh, &gl);

  float wl0 = p.wlin[mr];
  float wl1 = p.wlin[mr + 16];
  float bl = p.blin[0];

  f32x4 acc[8];
#pragma unroll 2
  for (int nt = 0; nt < 8; ++nt) {
    float bv = p.bias[nt * 16 + mr];
    f32x4 a;
    a[0] = bv; a[1] = bv; a[2] = bv; a[3] = bv;
    bf16x8 b0h = as_bf16x8(p.fh[nt * 64 + lane]);
    bf16x8 b0l = as_bf16x8(p.fl[nt * 64 + lane]);
    bf16x8 b1h = as_bf16x8(p.fh[(8 + nt) * 64 + lane]);
    bf16x8 b1l = as_bf16x8(p.fl[(8 + nt) * 64 + lane]);
    bf16x8 t0h = as_bf16x8(p.fh[(16 + nt) * 64 + lane]);
    bf16x8 t0l = as_bf16x8(p.fl[(16 + nt) * 64 + lane]);
    bf16x8 t1h = as_bf16x8(p.fh[(24 + nt) * 64 + lane]);
    bf16x8 t1l = as_bf16x8(p.fl[(24 + nt) * 64 + lane]);
    a = MFMA(xh[0], b0h, a); a = MFMA(xh[0], b0l, a); a = MFMA(xl[0], b0h, a);
    a = MFMA(xh[1], b1h, a); a = MFMA(xh[1], b1l, a); a = MFMA(xl[1], b1h, a);
    a = MFMA(hh, t0h, a);    a = MFMA(hh, t0l, a);    a = MFMA(hl, t0h, a);
    a = MFMA(gh, t1h, a);    a = MFMA(gh, t1l, a);    a = MFMA(gl, t1h, a);
    acc[nt] = a;
  }

  // Epilogue: lane holds cols mr (tile 2g) and mr+16 (tile 2g+1) of gate g,
  // rows quad*4+r. All four gates' z in-lane.
#pragma unroll
  for (int r = 0; r < 4; ++r) {
    int node = m0 + quad * 4 + r;
    int nc = node < NN ? node : NN - 1;
    float c0 = p.cst[nc * 32 + mr];
    float c1 = p.cst[nc * 32 + 16 + mr];
    float I0 = sigm(acc[0][r]), I1 = sigm(acc[1][r]);
    float F0 = sigm(acc[2][r]), F1 = sigm(acc[3][r]);
    float T0 = tanhf(acc[4][r]), T1 = tanhf(acc[5][r]);
    float O0 = sigm(acc[6][r]), O1 = sigm(acc[7][r]);
    float C0 = fmaf(F0, c0, I0 * T0);
    float C1 = fmaf(F1, c1, I1 * T1);
    float H0 = O0 * tanhf(C0);
    float H1 = O1 * tanhf(C1);
    float part = fmaf(fmaxf(H0, 0.f), wl0, fmaxf(H1, 0.f) * wl1);
#pragma unroll
    for (int s = 1; s < 16; s <<= 1) part += __shfl_xor(part, s, 64);
    if (mr == 0 && node < NN) p.out[node] = part + bl;
  }
}

extern "C" void kernel_launch(void* const* d_in, const int* in_sizes, int n_in,
                              void* d_out, int out_size, void* d_ws, size_t ws_size,
                              hipStream_t stream) {
  const float* x = (const float*)d_in[0];
  const int* row = (const int*)d_in[1];
  const int* col = row + NE;
  const float* ew = (const float*)d_in[2];
  const float* h = (const float*)d_in[3];
  const float* c = (const float*)d_in[4];

  // Workspace layout (4-byte units), total 30.4 MB (R4-proven footprint).
  // fh/fl/bias OVERLAY the rank16 region: rank16 is dead after k_reorder,
  // and k_prep runs after k_reorder. (R5 bug: fh/fl overlapped each other.)
  float* ws = (float*)d_ws;
  unsigned long long* packed = (unsigned long long*)ws;     // uint64[NN]
  float* dis = ws + 2 * NN;
  int* rowptr = (int*)(ws + 3 * NN);
  unsigned short* rank16 = (unsigned short*)(ws + 400004);  // ushort[NE]: [400004,1200004)
  uint4* fh = (uint4*)(ws + 400004);                        // 8192 floats: [400004,408196)
  uint4* fl = (uint4*)(ws + 408196);                        // 8192 floats: [408196,416388)
  float* biasws = ws + 416388;                              // 128: [416388,416516)
  int* bsum = (int*)(ws + 1200004);
  int* boff = bsum + 512;
  int2* colw = (int2*)(ws + 1201032);                       // 12.8 MB
  float* agg = ws + 1201032 + 2 * NE;                       // 12.8 MB, 16B-aligned

  hipMemsetAsync(packed, 0, NN * sizeof(unsigned long long), stream);

  k_hist<<<NE / 256, 256, 0, stream>>>(row, ew, packed, rank16);
  k_scan1<<<NBLK, 256, 0, stream>>>(packed, bsum);
  k_scan2<<<1, 512, 0, stream>>>(bsum, boff);
  k_scan3<<<NBLK, 256, 0, stream>>>(packed, boff, rowptr, dis);
  k_reorder<<<NE / 256, 256, 0, stream>>>(row, col, ew, rank16, rowptr, dis, colw);

  // k_prep AFTER k_reorder: its outputs overlay the now-dead rank16.
  PrepParams pp;
  for (int g = 0; g < 4; ++g) {
    pp.W[g] = (const float*)d_in[5 + 4 * g];
    pp.b[g] = (const float*)d_in[6 + 4 * g];
    pp.T0[g] = (const float*)d_in[7 + 4 * g];
    pp.T1[g] = pp.T0[g] + 1024;
    pp.cb[g] = (const float*)d_in[8 + 4 * g];
  }
  pp.fh = fh;
  pp.fl = fl;
  pp.bias = biasws;
  k_prep<<<8, 256, 0, stream>>>(pp);

  k_agg<<<(NN + 3) / 4, 256, 0, stream>>>(rowptr, colw, (const float4*)h,
                                          (float4*)agg);

  GmmParams gp;
  gp.x4 = (const float4*)x;
  gp.h4 = (const float4*)h;
  gp.agg4 = (const float4*)agg;
  gp.cst = c;
  gp.fh = fh;
  gp.fl = fl;
  gp.bias = biasws;
  gp.wlin = (const float*)d_in[21];
  gp.blin = (const float*)d_in[22];
  gp.out = (float*)d_out;
  k_gmm<<<(NN + 63) / 64, 256, 0, stream>>>(gp);
}